// Round 6
// baseline (210.262 us; speedup 1.0000x reference)
//
#include <hip/hip_runtime.h>

#define GRID_N 112
#define O_MAX 48
#define HW_N (GRID_N * GRID_N)   // 12544
#define NT 256
#define LSTR 72                  // table row stride in f16 (144 B, 16B-aligned rows)

typedef _Float16 half8  __attribute__((ext_vector_type(8)));
typedef _Float16 half2v __attribute__((ext_vector_type(2)));
typedef float    f32x4  __attribute__((ext_vector_type(4)));

// channel[b,h,w] = 0.5 + sum_k A[h,k]*B[w,k], masked by road_mask.
// Tables (f16, signed): k<n -> -0.5*obj gauss / plain gauss; k==n -> +0.5*goal; k>n -> 0.
// MFMA operands SWAPPED (A=ey rows, B=ex rows) so D rows map to w:
// lane(m,quad) holds C[h=th*16+m][w=tw*16+quad*4+r] -> float4 stores, int4 mask loads.
__global__ __launch_bounds__(NT) void goalmap_kernel(
    const float* __restrict__ xL, const float* __restrict__ yL,
    const float* __restrict__ obj_list, const int* __restrict__ obj_num,
    const int* __restrict__ road_mask, float* __restrict__ out)
{
    constexpr float INV = 1.0f / (2.0f * 5.0f * 5.0f);  // SIGMA = 5.0

    __shared__ _Float16 exT[GRID_N * LSTR];   // [h][k]  16128 B
    __shared__ _Float16 eyT[GRID_N * LSTR];   // [w][k]  16128 B

    const int b   = blockIdx.x;
    const int tid = threadIdx.x;
    const int n   = obj_num[b];               // block-uniform
    const bool k64 = (n >= 32);
    const float xl = xL[b];
    const float yl = yL[b];
    const float* ob = obj_list + (size_t)b * O_MAX * 2;

    const int lane = tid & 63;
    const int wid  = tid >> 6;                // 4 waves
    const int m    = lane & 15;
    const int quad = lane >> 4;

    // contiguous tile ranges per wave: 13,13,13,10 of 49 (tw sweeps fastest)
    const int start = wid * 13;
    const int cnt   = (wid < 3) ? 13 : 10;

    const int4*   rm4 = (const int4*)(road_mask + (size_t)b * HW_N);
    float4*       op4 = (float4*)(out + (size_t)b * HW_N);

    // --- (1) prefetch all mask int4s this wave needs (13 x 1KB/wave in flight) ---
    int4 mpf[13];
    #pragma unroll
    for (int i = 0; i < 13; ++i) {
        if (i < cnt) {                         // wave-uniform guard
            int t  = start + i;
            int th = t / 7, tw = t - th * 7;
            mpf[i] = rm4[(th * 16 + m) * 28 + tw * 4 + quad];
        }
    }

    // --- (2) build signed f16 tables [pos][k]; only k<32 half if n<32 ---
    const int sh = k64 ? 5 : 4;               // pairs per position: 32 or 16
    const int items = GRID_N << sh;           // 112 * (Keff/2)
    for (int i = tid; i < items; i += NT) {
        int pos = i >> sh;
        int o0  = (i & ((1 << sh) - 1)) * 2;
        half2v vx, vy;
        #pragma unroll
        for (int j = 0; j < 2; ++j) {
            int o = o0 + j;
            float valx = 0.f, valy = 0.f;
            if (o <= n) {
                float cx, cy, s;
                if (o < n) {
                    float2 c = *(const float2*)&ob[o * 2];
                    cx = c.y; cy = c.x; s = -0.5f;
                } else {
                    cx = xl; cy = yl; s = 0.5f;
                }
                float dx = (float)pos - cx;
                float dy = (float)pos - cy;
                valx = s * __expf(-dx * dx * INV);
                valy =     __expf(-dy * dy * INV);
            }
            vx[j] = (_Float16)valx;
            vy[j] = (_Float16)valy;
        }
        *(half2v*)&exT[pos * LSTR + o0] = vx;
        *(half2v*)&eyT[pos * LSTR + o0] = vy;
    }
    __syncthreads();

    // --- (3) MFMA + masked float4 stores ---
    #pragma unroll
    for (int i = 0; i < 13; ++i) {
        if (i < cnt) {                         // wave-uniform
            int t  = start + i;
            int th = t / 7, tw = t - th * 7;

            const _Float16* arow = &eyT[(tw * 16 + m) * LSTR + quad * 8]; // A = ey
            const _Float16* brow = &exT[(th * 16 + m) * LSTR + quad * 8]; // B = ex
            half8 a0 = *(const half8*)arow;
            half8 b0 = *(const half8*)brow;

            f32x4 acc = {0.f, 0.f, 0.f, 0.f};
            acc = __builtin_amdgcn_mfma_f32_16x16x32_f16(a0, b0, acc, 0, 0, 0);
            if (k64) {
                half8 a1 = *(const half8*)(arow + 32);
                half8 b1 = *(const half8*)(brow + 32);
                acc = __builtin_amdgcn_mfma_f32_16x16x32_f16(a1, b1, acc, 0, 0, 0);
            }

            int4 mv = mpf[i];
            float4 v;
            v.x = (mv.x == 0) ? 0.f : 0.5f + acc[0];
            v.y = (mv.y == 0) ? 0.f : 0.5f + acc[1];
            v.z = (mv.z == 0) ? 0.f : 0.5f + acc[2];
            v.w = (mv.w == 0) ? 0.f : 0.5f + acc[3];
            op4[(th * 16 + m) * 28 + tw * 4 + quad] = v;
        }
    }
}

extern "C" void kernel_launch(void* const* d_in, const int* in_sizes, int n_in,
                              void* d_out, int out_size, void* d_ws, size_t ws_size,
                              hipStream_t stream) {
    const float* xL        = (const float*)d_in[0];
    const float* yL        = (const float*)d_in[1];
    const float* obj_list  = (const float*)d_in[2];
    const int*   obj_num   = (const int*)d_in[3];
    const int*   road_mask = (const int*)d_in[4];
    float*       out       = (float*)d_out;
    const int B = in_sizes[0];  // 2048

    goalmap_kernel<<<B, NT, 0, stream>>>(xL, yL, obj_list, obj_num, road_mask, out);
}